// Round 6
// baseline (46.911 us; speedup 1.0000x reference)
//
#include <hip/hip_runtime.h>

#define S_LEN   512
#define NSTEP   511
#define B_SZ    64
#define HIDDEN  256
#define OUT_CH  32
#define GBASE   4368

// ws layout (bytes): c_ws[64][88] @ 0 (22528); V_ws[2][16][16][256] @ 22528
// (524288); U2_ws[2][16][4][256] @ 546816 (131072). Total 677888.
#define V_OFF   22528
#define U2_OFF  546816

// ---------------------------------------------------------------------------
// Kernel 1, two block roles:
//  blocks 0..127  (transform): block = (g, p, 64-col chunk).
//    stage A: U[q][ck][col] = sum_r M[r][ck] w1[g,272+p*256+q*16+r][col]
//    stage B: V[g][p][cj*4+ck][col] = sum_q M[q][cj] U[q][ck][col]
//    level2 : U2[g][p][cb][col]     = sum_q M[q][cb] w1[g,16+p*16+q][col]
//    All w1 reads are 256 B contiguous per 64-lane group (coalesced, each
//    element read once for level-3).
//  blocks 128..191 (core signature): verified depth-3 scan of u=[1/511,dx],
//    4 waves x 128-step segments + wave-0 Chen combine -> c_ws[b][88].
// ---------------------------------------------------------------------------
__global__ __launch_bounds__(256) void prep_kernel(
    const float* __restrict__ x,          // (64, 512, 3)
    const void*  __restrict__ lengths_raw,// (64,) int32 or int64
    const float* __restrict__ aug_w,      // (2, 12, 3)
    const float* __restrict__ w1,         // (8736, 256)
    float* __restrict__ c_ws,             // (64, 88)
    float* __restrict__ V_ws,             // (2, 16, 16, 256)
    float* __restrict__ U2_ws)            // (2, 16, 4, 256)
{
    __shared__ float Ms[2][16][4];
    __shared__ union {
        struct { float U[16][4][64]; } t;                       // 16 KB
        struct { float xs[S_LEN * 3];                           // 6 KB
                 float u[NSTEP * 4 + 4];                        // 8 KB
                 float seg[4][88]; } s;                         // 1.4 KB
    } sm;

    const int bx  = blockIdx.x;
    const int tid = threadIdx.x;

    // build M for both groups: rows [time; I3; aug_w]
    if (tid < 32) {
        const int g = tid >> 4, row = tid & 15;
        float4 m;
        if (row == 0)      m = make_float4(1.f, 0.f, 0.f, 0.f);
        else if (row < 4)  m = make_float4(0.f, row == 1 ? 1.f : 0.f,
                                                row == 2 ? 1.f : 0.f,
                                                row == 3 ? 1.f : 0.f);
        else {
            const float* aw = aug_w + g * 36 + (row - 4) * 3;
            m = make_float4(0.f, aw[0], aw[1], aw[2]);
        }
        *(float4*)&Ms[g][row][0] = m;
    }
    __syncthreads();

    if (bx < 128) {
        // -------- transform branch --------
        const int g  = bx >> 6, rem = bx & 63;
        const int p  = rem >> 2, cc = rem & 3;
        const int col = tid & 63, col0 = cc * 64;
        const int qg  = tid >> 6;          // 0..3

        // stage A
        const float* wbase = w1 + (size_t)(g * GBASE + 272 + p * 256) * HIDDEN + col0 + col;
        #pragma unroll
        for (int qi = 0; qi < 4; ++qi) {
            const int q = qg * 4 + qi;
            float wv[16];
            #pragma unroll
            for (int r = 0; r < 16; ++r)
                wv[r] = wbase[(size_t)(q * 16 + r) * HIDDEN];
            float4 acc = make_float4(0.f, 0.f, 0.f, 0.f);
            #pragma unroll
            for (int r = 0; r < 16; ++r) {
                const float4 m = *(const float4*)&Ms[g][r][0];
                acc.x = fmaf(m.x, wv[r], acc.x);
                acc.y = fmaf(m.y, wv[r], acc.y);
                acc.z = fmaf(m.z, wv[r], acc.z);
                acc.w = fmaf(m.w, wv[r], acc.w);
            }
            sm.t.U[q][0][col] = acc.x;
            sm.t.U[q][1][col] = acc.y;
            sm.t.U[q][2][col] = acc.z;
            sm.t.U[q][3][col] = acc.w;
        }
        __syncthreads();

        // stage B
        #pragma unroll
        for (int ti = 0; ti < 4; ++ti) {
            const int t = qg * 4 + ti, cj = t >> 2, ck = t & 3;
            float acc = 0.f;
            #pragma unroll
            for (int q = 0; q < 16; ++q)
                acc = fmaf(Ms[g][q][cj], sm.t.U[q][ck][col], acc);
            V_ws[(size_t)((g * 16 + p) * 16 + t) * HIDDEN + col0 + col] = acc;
        }

        // level-2 (4 waves read the same 16 rows; 4x redundancy absorbed by L2)
        {
            const int cb = qg;
            const float* w2base = w1 + (size_t)(g * GBASE + 16 + p * 16) * HIDDEN + col0 + col;
            float wq[16];
            #pragma unroll
            for (int q = 0; q < 16; ++q)
                wq[q] = w2base[(size_t)q * HIDDEN];
            float acc = 0.f;
            #pragma unroll
            for (int q = 0; q < 16; ++q)
                acc = fmaf(Ms[g][q][cb], wq[q], acc);
            U2_ws[(size_t)((g * 16 + p) * 4 + cb) * HIDDEN + col0 + col] = acc;
        }
    } else {
        // -------- core signature branch --------
        const int b = bx - 128;

        // lengths dtype detect: all lengths >= 2 -> if word1 == 0 it's int64.
        const int* l32 = (const int*)lengths_raw;
        const int  len = (l32[1] == 0) ? l32[2 * b] : l32[b];
        const int  lastIdx = len - 1;

        for (int idx = tid; idx < 384; idx += 256)
            ((float4*)sm.s.xs)[idx] = ((const float4*)(x + (size_t)b * S_LEN * 3))[idx];
        __syncthreads();

        for (int s = tid; s < NSTEP; s += 256) {
            float dx0 = 0.f, dx1 = 0.f, dx2 = 0.f;
            if (s < lastIdx) {             // become-constant trick => dx = 0
                dx0 = sm.s.xs[(s + 1) * 3 + 0] - sm.s.xs[s * 3 + 0];
                dx1 = sm.s.xs[(s + 1) * 3 + 1] - sm.s.xs[s * 3 + 1];
                dx2 = sm.s.xs[(s + 1) * 3 + 2] - sm.s.xs[s * 3 + 2];
            }
            *(float4*)&sm.s.u[s * 4] = make_float4(1.0f / 511.0f, dx0, dx1, dx2);
        }
        __syncthreads();

        const int wid = tid >> 6, lane = tid & 63;
        const int a   = lane >> 4;
        const int bb  = (lane >> 2) & 3;
        const int c   = lane & 3;
        {
            const int s0   = wid * 128;
            const int nloc = min(128, NSTEP - s0);   // 128,128,128,127
            float r1 = 0.f, r2 = 0.f, r3 = 0.f;
            for (int s = s0; s < s0 + nloc; ++s) {
                const float da = sm.s.u[s * 4 + a];
                const float db = sm.s.u[s * 4 + bb];
                const float dc = sm.s.u[s * 4 + c];
                const float t  = fmaf(db, fmaf(r1, 0.5f, da * (1.f / 6.f)), r2);
                r3 = fmaf(t, dc, r3);
                r2 = fmaf(db, fmaf(da, 0.5f, r1), r2);
                r1 += da;
            }
            sm.s.seg[wid][20 + lane] = r3;
            if (c == 0)            sm.s.seg[wid][4 + a * 4 + bb] = r2;
            if (bb == 0 && c == 0) sm.s.seg[wid][a]              = r1;
        }
        __syncthreads();

        if (wid == 0) {
            float A1 = sm.s.seg[0][a];
            float A2 = sm.s.seg[0][4 + a * 4 + bb];
            float A3 = sm.s.seg[0][20 + lane];
            #pragma unroll
            for (int sg = 1; sg < 4; ++sg) {
                const float* S = sm.s.seg[sg];
                const float B1a  = S[a];
                const float B1b  = S[bb];
                const float B1c  = S[c];
                const float B2ab = S[4 + a * 4 + bb];
                const float B2bc = S[4 + bb * 4 + c];
                const float B3   = S[20 + lane];
                A3 = fmaf(A1, B2bc, fmaf(A2, B1c, A3 + B3));  // OLD A1, A2
                A2 = fmaf(A1, B1b, A2 + B2ab);                // OLD A1
                A1 = A1 + B1a;
            }
            c_ws[b * 88 + 20 + lane] = A3;
            if (c == 0)            c_ws[b * 88 + 4 + a * 4 + bb] = A2;
            if (bb == 0 && c == 0) c_ws[b * 88 + a]              = A1;
        }
    }
}

// ---------------------------------------------------------------------------
// Kernel 2: per batch b.  D3[g][p][t] = sum_ci M[p][ci] C3[ci][t] (4-term);
// D2[g][p][cb] = sum_ca M[p][ca] C2[ca][cb]; E1[g][p] = sum_a M[p][a] C1[a].
// h[col] = b1 + sum_g { sum_p E1.w1row + sum D2.U2 + sum D3.V }  (672 FMA,
// coalesced L2-hot reads), ReLU, then h @ w2 + b2 (verified 8-way split).
// ---------------------------------------------------------------------------
__global__ __launch_bounds__(256) void mix_kernel(
    const float* __restrict__ c_ws,   // (64, 88)
    const float* __restrict__ V_ws,   // (2, 16, 16, 256)
    const float* __restrict__ U2_ws,  // (2, 16, 4, 256)
    const float* __restrict__ aug_w,  // (2, 12, 3)
    const float* __restrict__ w1,     // (8736, 256)
    const float* __restrict__ b1,     // (256,)
    const float* __restrict__ w2,     // (256, 32)
    const float* __restrict__ b2,     // (32,)
    float* __restrict__ outp)         // (64, 32)
{
    __shared__ float Ms[2][16][4];
    __shared__ float sC[88];
    __shared__ float E1[2][16];
    __shared__ float D2[2][16][4];
    __shared__ float D3[2][16][16];
    __shared__ float s_h[HIDDEN];
    __shared__ float s_p[8][33];

    const int b   = blockIdx.x;
    const int tid = threadIdx.x;

    if (tid < 32) {
        const int g = tid >> 4, row = tid & 15;
        float4 m;
        if (row == 0)      m = make_float4(1.f, 0.f, 0.f, 0.f);
        else if (row < 4)  m = make_float4(0.f, row == 1 ? 1.f : 0.f,
                                                row == 2 ? 1.f : 0.f,
                                                row == 3 ? 1.f : 0.f);
        else {
            const float* aw = aug_w + g * 36 + (row - 4) * 3;
            m = make_float4(0.f, aw[0], aw[1], aw[2]);
        }
        *(float4*)&Ms[g][row][0] = m;
    }
    if (tid >= 128 && tid < 216) sC[tid - 128] = c_ws[b * 88 + tid - 128];
    __syncthreads();

    // D3: 512 entries, 2 per thread. C3[ci][t] = sC[20 + ci*16 + t].
    #pragma unroll
    for (int rep = 0; rep < 2; ++rep) {
        const int e = tid + rep * 256;
        const int g = e >> 8, r = e & 255, p = r >> 4, t = r & 15;
        D3[g][p][t] = fmaf(Ms[g][p][0], sC[20 + t],
                      fmaf(Ms[g][p][1], sC[36 + t],
                      fmaf(Ms[g][p][2], sC[52 + t],
                            Ms[g][p][3] * sC[68 + t])));
    }
    if (tid < 128) {
        // D2: C2[ca][cb] = sC[4 + ca*4 + cb]
        const int g = tid >> 6, r = tid & 63, p = r >> 2, cb = r & 3;
        D2[g][p][cb] = fmaf(Ms[g][p][0], sC[4 + cb],
                       fmaf(Ms[g][p][1], sC[8 + cb],
                       fmaf(Ms[g][p][2], sC[12 + cb],
                             Ms[g][p][3] * sC[16 + cb])));
    } else if (tid < 160) {
        const int e = tid - 128, g = e >> 4, p = e & 15;
        E1[g][p] = fmaf(Ms[g][p][0], sC[0],
                   fmaf(Ms[g][p][1], sC[1],
                   fmaf(Ms[g][p][2], sC[2], Ms[g][p][3] * sC[3])));
    }
    __syncthreads();

    const int col = tid;
    float a1 = b1[col], a2 = 0.f, a3 = 0.f;
    #pragma unroll
    for (int g = 0; g < 2; ++g) {
        #pragma unroll
        for (int p = 0; p < 16; ++p)
            a1 = fmaf(E1[g][p], w1[(size_t)(g * GBASE + p) * HIDDEN + col], a1);
        #pragma unroll 8
        for (int e = 0; e < 64; ++e)       // e = p*4 + cb
            a2 = fmaf(((const float*)D2[g])[e],
                      U2_ws[(size_t)(g * 64 + e) * HIDDEN + col], a2);
        #pragma unroll 8
        for (int e = 0; e < 256; ++e)      // e = p*16 + t
            a3 = fmaf(((const float*)D3[g])[e],
                      V_ws[(size_t)(g * 256 + e) * HIDDEN + col], a3);
    }
    s_h[col] = fmaxf(a1 + a2 + a3, 0.f);
    __syncthreads();

    const int o = tid & 31, part = tid >> 5;
    float pacc = 0.f;
    #pragma unroll
    for (int jj = 0; jj < 32; ++jj)
        pacc = fmaf(s_h[part * 32 + jj], w2[(part * 32 + jj) * OUT_CH + o], pacc);
    s_p[part][o] = pacc;
    __syncthreads();

    if (tid < OUT_CH) {
        float oacc = b2[tid];
        #pragma unroll
        for (int q = 0; q < 8; ++q) oacc += s_p[q][tid];
        outp[b * OUT_CH + tid] = oacc;
    }
}

extern "C" void kernel_launch(void* const* d_in, const int* in_sizes, int n_in,
                              void* d_out, int out_size, void* d_ws, size_t ws_size,
                              hipStream_t stream) {
    const float* x       = (const float*)d_in[0];
    const void*  lengths = d_in[1];
    const float* aug_w   = (const float*)d_in[2];
    // d_in[3] = aug_b: bias cancels in increments, unused.
    const float* w1      = (const float*)d_in[4];
    const float* b1      = (const float*)d_in[5];
    const float* w2      = (const float*)d_in[6];
    const float* b2      = (const float*)d_in[7];

    float* c_ws  = (float*)d_ws;
    float* V_ws  = (float*)((char*)d_ws + V_OFF);
    float* U2_ws = (float*)((char*)d_ws + U2_OFF);

    prep_kernel<<<192, 256, 0, stream>>>(x, lengths, aug_w, w1, c_ws, V_ws, U2_ws);
    mix_kernel<<<B_SZ, 256, 0, stream>>>(c_ws, V_ws, U2_ws, aug_w, w1, b1, w2, b2,
                                         (float*)d_out);
}

// Round 7
// 25.143 us; speedup vs baseline: 1.8657x; 1.8657x over previous
//
#include <hip/hip_runtime.h>

#define S_LEN   512
#define NSTEP   511
#define B_SZ    64
#define HIDDEN  256
#define OUT_CH  32
#define GBASE   4368

// ws layout (bytes): c_ws[64][88] @ 0 (22528); V_ws[2][16][16][256] @ 22528
// (524288); U2_ws[2][16][4][256] @ 546816 (131072). Total 677888.
#define V_OFF   22528
#define U2_OFF  546816

// ---------------------------------------------------------------------------
// Kernel 1, two block roles:
//  blocks 0..127  (transform): block = (g, p, 64-col chunk), thread=(q,c4).
//    stage A: U[q][ck][c4] = sum_r M[r][ck] w1[g,272+p*256+q*16+r][cols]  (f4)
//    stage B: V[g][p][cj*4+ck][cols] = sum_q M[q][cj] U[q][ck][c4]       (f4)
//    level2 : U2[g][p][cb][cols]     = sum_q M[q][cb] w1[g,16+p*16+q][cols]
//  blocks 128..191 (core signature): verified depth-3 scan of u=[1/511,dx],
//    4 waves x 128-step segments + wave-0 Chen combine -> c_ws[b][88].
// ---------------------------------------------------------------------------
__global__ __launch_bounds__(256) void prep_kernel(
    const float* __restrict__ x,          // (64, 512, 3)
    const void*  __restrict__ lengths_raw,// (64,) int32 or int64
    const float* __restrict__ aug_w,      // (2, 12, 3)
    const float* __restrict__ w1,         // (8736, 256)
    float* __restrict__ c_ws,             // (64, 88)
    float* __restrict__ V_ws,             // (2, 16, 16, 256)
    float* __restrict__ U2_ws)            // (2, 16, 4, 256)
{
    __shared__ float Ms[2][16][4];
    __shared__ union {
        struct { float4 U[16][4][16]; } t;                      // 16 KB
        struct { float xs[S_LEN * 3];                           // 6 KB
                 float u[NSTEP * 4 + 4];                        // 8 KB
                 float seg[4][88]; } s;                         // 1.4 KB
    } sm;

    const int bx  = blockIdx.x;
    const int tid = threadIdx.x;

    // build M for both groups: rows [time; I3; aug_w]
    if (tid < 32) {
        const int g = tid >> 4, row = tid & 15;
        float4 m;
        if (row == 0)      m = make_float4(1.f, 0.f, 0.f, 0.f);
        else if (row < 4)  m = make_float4(0.f, row == 1 ? 1.f : 0.f,
                                                row == 2 ? 1.f : 0.f,
                                                row == 3 ? 1.f : 0.f);
        else {
            const float* aw = aug_w + g * 36 + (row - 4) * 3;
            m = make_float4(0.f, aw[0], aw[1], aw[2]);
        }
        *(float4*)&Ms[g][row][0] = m;
    }
    __syncthreads();

    if (bx < 128) {
        // -------- transform branch --------
        const int g  = bx >> 6, rem = bx & 63;
        const int p  = rem >> 2, cc = rem & 3;
        const int col0 = cc * 64;
        const int c4 = tid & 15;            // float4 column group
        const int t  = tid >> 4;            // 0..15

        // stage A (q = t): 16 float4 loads, 4 float4 accumulators
        {
            const int q = t;
            const float* wbase = w1 + (size_t)(g * GBASE + 272 + p * 256 + q * 16) * HIDDEN
                                    + col0 + c4 * 4;
            float4 wv[16];
            #pragma unroll
            for (int r = 0; r < 16; ++r)
                wv[r] = *(const float4*)(wbase + (size_t)r * HIDDEN);
            #pragma unroll
            for (int ck = 0; ck < 4; ++ck) {
                float4 acc = make_float4(0.f, 0.f, 0.f, 0.f);
                #pragma unroll
                for (int r = 0; r < 16; ++r) {
                    const float m = Ms[g][r][ck];
                    acc.x = fmaf(m, wv[r].x, acc.x);
                    acc.y = fmaf(m, wv[r].y, acc.y);
                    acc.z = fmaf(m, wv[r].z, acc.z);
                    acc.w = fmaf(m, wv[r].w, acc.w);
                }
                sm.t.U[q][ck][c4] = acc;
            }
        }
        __syncthreads();

        // stage B: thread (t, c4): cj = t>>2, ck = t&3
        {
            const int cj = t >> 2, ck = t & 3;
            float4 acc = make_float4(0.f, 0.f, 0.f, 0.f);
            #pragma unroll
            for (int q = 0; q < 16; ++q) {
                const float m = Ms[g][q][cj];
                const float4 uv = sm.t.U[q][ck][c4];
                acc.x = fmaf(m, uv.x, acc.x);
                acc.y = fmaf(m, uv.y, acc.y);
                acc.z = fmaf(m, uv.z, acc.z);
                acc.w = fmaf(m, uv.w, acc.w);
            }
            *(float4*)(V_ws + (size_t)((g * 16 + p) * 16 + t) * HIDDEN + col0 + c4 * 4) = acc;
        }

        // level-2: wave 0 (t < 4), cb = t
        if (t < 4) {
            const float* w2b = w1 + (size_t)(g * GBASE + 16 + p * 16) * HIDDEN + col0 + c4 * 4;
            float4 acc = make_float4(0.f, 0.f, 0.f, 0.f);
            #pragma unroll
            for (int q = 0; q < 16; ++q) {
                const float m = Ms[g][q][t];
                const float4 wv = *(const float4*)(w2b + (size_t)q * HIDDEN);
                acc.x = fmaf(m, wv.x, acc.x);
                acc.y = fmaf(m, wv.y, acc.y);
                acc.z = fmaf(m, wv.z, acc.z);
                acc.w = fmaf(m, wv.w, acc.w);
            }
            *(float4*)(U2_ws + (size_t)((g * 16 + p) * 4 + t) * HIDDEN + col0 + c4 * 4) = acc;
        }
    } else {
        // -------- core signature branch (verified) --------
        const int b = bx - 128;

        // lengths dtype detect: all lengths >= 2 -> if word1 == 0 it's int64.
        const int* l32 = (const int*)lengths_raw;
        const int  len = (l32[1] == 0) ? l32[2 * b] : l32[b];
        const int  lastIdx = len - 1;

        for (int idx = tid; idx < 384; idx += 256)
            ((float4*)sm.s.xs)[idx] = ((const float4*)(x + (size_t)b * S_LEN * 3))[idx];
        __syncthreads();

        for (int s = tid; s < NSTEP; s += 256) {
            float dx0 = 0.f, dx1 = 0.f, dx2 = 0.f;
            if (s < lastIdx) {             // become-constant trick => dx = 0
                dx0 = sm.s.xs[(s + 1) * 3 + 0] - sm.s.xs[s * 3 + 0];
                dx1 = sm.s.xs[(s + 1) * 3 + 1] - sm.s.xs[s * 3 + 1];
                dx2 = sm.s.xs[(s + 1) * 3 + 2] - sm.s.xs[s * 3 + 2];
            }
            *(float4*)&sm.s.u[s * 4] = make_float4(1.0f / 511.0f, dx0, dx1, dx2);
        }
        __syncthreads();

        const int wid = tid >> 6, lane = tid & 63;
        const int a   = lane >> 4;
        const int bb  = (lane >> 2) & 3;
        const int c   = lane & 3;
        {
            const int s0   = wid * 128;
            const int nloc = min(128, NSTEP - s0);   // 128,128,128,127
            float r1 = 0.f, r2 = 0.f, r3 = 0.f;
            for (int s = s0; s < s0 + nloc; ++s) {
                const float da = sm.s.u[s * 4 + a];
                const float db = sm.s.u[s * 4 + bb];
                const float dc = sm.s.u[s * 4 + c];
                const float t2 = fmaf(db, fmaf(r1, 0.5f, da * (1.f / 6.f)), r2);
                r3 = fmaf(t2, dc, r3);
                r2 = fmaf(db, fmaf(da, 0.5f, r1), r2);
                r1 += da;
            }
            sm.s.seg[wid][20 + lane] = r3;
            if (c == 0)            sm.s.seg[wid][4 + a * 4 + bb] = r2;
            if (bb == 0 && c == 0) sm.s.seg[wid][a]              = r1;
        }
        __syncthreads();

        if (wid == 0) {
            float A1 = sm.s.seg[0][a];
            float A2 = sm.s.seg[0][4 + a * 4 + bb];
            float A3 = sm.s.seg[0][20 + lane];
            #pragma unroll
            for (int sg = 1; sg < 4; ++sg) {
                const float* S = sm.s.seg[sg];
                const float B1a  = S[a];
                const float B1b  = S[bb];
                const float B1c  = S[c];
                const float B2ab = S[4 + a * 4 + bb];
                const float B2bc = S[4 + bb * 4 + c];
                const float B3   = S[20 + lane];
                A3 = fmaf(A1, B2bc, fmaf(A2, B1c, A3 + B3));  // OLD A1, A2
                A2 = fmaf(A1, B1b, A2 + B2ab);                // OLD A1
                A1 = A1 + B1a;
            }
            c_ws[b * 88 + 20 + lane] = A3;
            if (c == 0)            c_ws[b * 88 + 4 + a * 4 + bb] = A2;
            if (bb == 0 && c == 0) c_ws[b * 88 + a]              = A1;
        }
    }
}

// ---------------------------------------------------------------------------
// Kernel 2: per batch b, 1024 threads. Coefficients D3/D2/E1 as in R6
// (verified). Thread (ks = tid>>6, col4 = tid&63) owns 4 cols (float4) and
// 1/16 of the 336-row/group sum: 42 independent float4 loads. LDS-reduce the
// 16 partials -> h, ReLU, then h @ w2 + b2 (verified 8-way split).
// ---------------------------------------------------------------------------
__global__ __launch_bounds__(1024) void mix_kernel(
    const float* __restrict__ c_ws,   // (64, 88)
    const float* __restrict__ V_ws,   // (2, 16, 16, 256)
    const float* __restrict__ U2_ws,  // (2, 16, 4, 256)
    const float* __restrict__ aug_w,  // (2, 12, 3)
    const float* __restrict__ w1,     // (8736, 256)
    const float* __restrict__ b1,     // (256,)
    const float* __restrict__ w2,     // (256, 32)
    const float* __restrict__ b2,     // (32,)
    float* __restrict__ outp)         // (64, 32)
{
    __shared__ float Ms[2][16][4];
    __shared__ float sC[88];
    __shared__ float E1[2][16];
    __shared__ float D2[2][64];
    __shared__ float D3[2][256];
    __shared__ float4 sp[16][64];     // 16 KB
    __shared__ float s_h[HIDDEN];
    __shared__ float s_p[8][33];

    const int b   = blockIdx.x;
    const int tid = threadIdx.x;

    if (tid < 32) {
        const int g = tid >> 4, row = tid & 15;
        float4 m;
        if (row == 0)      m = make_float4(1.f, 0.f, 0.f, 0.f);
        else if (row < 4)  m = make_float4(0.f, row == 1 ? 1.f : 0.f,
                                                row == 2 ? 1.f : 0.f,
                                                row == 3 ? 1.f : 0.f);
        else {
            const float* aw = aug_w + g * 36 + (row - 4) * 3;
            m = make_float4(0.f, aw[0], aw[1], aw[2]);
        }
        *(float4*)&Ms[g][row][0] = m;
    }
    if (tid >= 64 && tid < 152) sC[tid - 64] = c_ws[b * 88 + tid - 64];
    __syncthreads();

    if (tid < 512) {
        const int g = tid >> 8, r = tid & 255, p = r >> 4, t = r & 15;
        D3[g][r] = fmaf(Ms[g][p][0], sC[20 + t],
                   fmaf(Ms[g][p][1], sC[36 + t],
                   fmaf(Ms[g][p][2], sC[52 + t],
                         Ms[g][p][3] * sC[68 + t])));
    } else if (tid < 640) {
        const int e = tid - 512, g = e >> 6, r = e & 63;
        const int p = r >> 2, cb = r & 3;
        D2[g][r] = fmaf(Ms[g][p][0], sC[4 + cb],
                   fmaf(Ms[g][p][1], sC[8 + cb],
                   fmaf(Ms[g][p][2], sC[12 + cb],
                         Ms[g][p][3] * sC[16 + cb])));
    } else if (tid < 672) {
        const int e = tid - 640, g = e >> 4, p = e & 15;
        E1[g][p] = fmaf(Ms[g][p][0], sC[0],
                   fmaf(Ms[g][p][1], sC[1],
                   fmaf(Ms[g][p][2], sC[2], Ms[g][p][3] * sC[3])));
    }
    __syncthreads();

    const int col4 = tid & 63, ks = tid >> 6;
    const int cb4  = col4 * 4;

    float4 acc = make_float4(0.f, 0.f, 0.f, 0.f);
    #pragma unroll
    for (int g = 0; g < 2; ++g) {
        {   // level-1: row ks
            const float e1 = E1[g][ks];
            const float4 wv = *(const float4*)(w1 + (size_t)(g * GBASE + ks) * HIDDEN + cb4);
            acc.x = fmaf(e1, wv.x, acc.x); acc.y = fmaf(e1, wv.y, acc.y);
            acc.z = fmaf(e1, wv.z, acc.z); acc.w = fmaf(e1, wv.w, acc.w);
        }
        #pragma unroll
        for (int m = 0; m < 4; ++m) {   // level-2: rows ks*4+m
            const float d2 = D2[g][ks * 4 + m];
            const float4 uv = *(const float4*)(U2_ws + (size_t)(g * 64 + ks * 4 + m) * HIDDEN + cb4);
            acc.x = fmaf(d2, uv.x, acc.x); acc.y = fmaf(d2, uv.y, acc.y);
            acc.z = fmaf(d2, uv.z, acc.z); acc.w = fmaf(d2, uv.w, acc.w);
        }
        #pragma unroll
        for (int m = 0; m < 16; ++m) {  // level-3: rows ks*16+m
            const float d3 = D3[g][ks * 16 + m];
            const float4 vv = *(const float4*)(V_ws + (size_t)(g * 256 + ks * 16 + m) * HIDDEN + cb4);
            acc.x = fmaf(d3, vv.x, acc.x); acc.y = fmaf(d3, vv.y, acc.y);
            acc.z = fmaf(d3, vv.z, acc.z); acc.w = fmaf(d3, vv.w, acc.w);
        }
    }
    sp[ks][col4] = acc;
    __syncthreads();

    if (tid < HIDDEN) {
        const int cq = tid >> 2, cm = tid & 3;
        float v = b1[tid];
        #pragma unroll
        for (int k = 0; k < 16; ++k)
            v += ((const float*)&sp[k][cq])[cm];
        s_h[tid] = fmaxf(v, 0.f);
    }
    __syncthreads();

    if (tid < 256) {
        const int o = tid & 31, part = tid >> 5;
        float pacc = 0.f;
        #pragma unroll
        for (int jj = 0; jj < 32; ++jj)
            pacc = fmaf(s_h[part * 32 + jj], w2[(part * 32 + jj) * OUT_CH + o], pacc);
        s_p[part][o] = pacc;
    }
    __syncthreads();

    if (tid < OUT_CH) {
        float oacc = b2[tid];
        #pragma unroll
        for (int q = 0; q < 8; ++q) oacc += s_p[q][tid];
        outp[b * OUT_CH + tid] = oacc;
    }
}

extern "C" void kernel_launch(void* const* d_in, const int* in_sizes, int n_in,
                              void* d_out, int out_size, void* d_ws, size_t ws_size,
                              hipStream_t stream) {
    const float* x       = (const float*)d_in[0];
    const void*  lengths = d_in[1];
    const float* aug_w   = (const float*)d_in[2];
    // d_in[3] = aug_b: bias cancels in increments, unused.
    const float* w1      = (const float*)d_in[4];
    const float* b1      = (const float*)d_in[5];
    const float* w2      = (const float*)d_in[6];
    const float* b2      = (const float*)d_in[7];

    float* c_ws  = (float*)d_ws;
    float* V_ws  = (float*)((char*)d_ws + V_OFF);
    float* U2_ws = (float*)((char*)d_ws + U2_OFF);

    prep_kernel<<<192, 256, 0, stream>>>(x, lengths, aug_w, w1, c_ws, V_ws, U2_ws);
    mix_kernel<<<B_SZ, 1024, 0, stream>>>(c_ws, V_ws, U2_ws, aug_w, w1, b1, w2, b2,
                                          (float*)d_out);
}